// Round 5
// baseline (93.797 us; speedup 1.0000x reference)
//
#include <hip/hip_runtime.h>

#define BB 8
#define NN 2048
#define DIN 128
#define DOUT 64
#define ALPHA_NS 0.2f
#define ITILE 16
#define JTILE 64
#define NWAVE 4
#define TTOT (NN / (JTILE * NWAVE))  // 8 tiles per wave
#define PACKBLK 2048                 // packer blocks in fused prep kernel

typedef __attribute__((ext_vector_type(4))) short short4v;
typedef __attribute__((ext_vector_type(4))) unsigned short ushort4v;
typedef __attribute__((ext_vector_type(4))) float float4v;

__device__ __forceinline__ unsigned short f32_to_bf16_rne(float x) {
  unsigned u = __builtin_bit_cast(unsigned, x);
  u += 0x7FFFu + ((u >> 16) & 1u);
  return (unsigned short)(u >> 16);
}

// ---- Fused prep kernel ----
// blocks [0, 2048): bit-pack adjacency (with mask_j folded):
//   packedC[(b*64 + i/32)*NN + j] bit r = (adj[b][i32*32+r][j]>0 && mask[b][j]>0)
// blocks [2048, 3072): z = h@W  -> zT tiles (bf16), s1, s2
__global__ __launch_bounds__(256, 4) void gat_prep(
    const float* __restrict__ h, const float* __restrict__ W,
    const float* __restrict__ a, const int* __restrict__ adj,
    const int* __restrict__ mask, unsigned* __restrict__ packedC,
    unsigned short* __restrict__ zT, float* __restrict__ s1,
    float* __restrict__ s2) {
  __shared__ float shbuf[6144];  // union: hS (8KB) + accW (16KB)
  const int tid = threadIdx.x;
  const int w = tid >> 6, lane = tid & 63;

  if (blockIdx.x < PACKBLK) {
    // ---- packer: wave-task = (b, iw, jc): 32 i-rows x 64 j ----
    const int gw = blockIdx.x * 4 + w;  // 0..8191
#pragma unroll 1
    for (int task = gw; task < BB * 64 * 32; task += PACKBLK * 4) {
      const int jc = task & 31;
      const int iw = (task >> 5) & 63;
      const int b = task >> 11;
      const int j = jc * 64 + lane;
      const unsigned mj = (mask[b * NN + j] > 0) ? 0xFFFFFFFFu : 0u;
      const int* ap = adj + ((long)(b * NN + iw * 32)) * NN + j;
      unsigned word = 0;
#pragma unroll
      for (int r = 0; r < 32; ++r)
        word |= (ap[(long)r * NN] > 0 ? 1u : 0u) << r;
      packedC[(size_t)(b * 64 + iw) * NN + j] = word & mj;
    }
    return;
  }

  // ---- zproj ----
  const int zbid = blockIdx.x - PACKBLK;  // 0..1023
  const long r0 = (long)zbid * 16;
  float (*hS)[DIN] = reinterpret_cast<float(*)[DIN]>(shbuf);            // 16x128
  float (*accW)[16][DOUT] =
      reinterpret_cast<float(*)[16][DOUT]>(shbuf + 16 * DIN);           // 4x16x64

  float Wr[32];
#pragma unroll
  for (int kk = 0; kk < 32; ++kk) Wr[kk] = W[(w * 32 + kk) * DOUT + lane];

  {
    const int r = tid >> 4, c = (tid & 15) * 8;
    const float* src = h + (r0 + r) * DIN + c;
    *reinterpret_cast<float4*>(&hS[r][c]) = *reinterpret_cast<const float4*>(src);
    *reinterpret_cast<float4*>(&hS[r][c + 4]) =
        *reinterpret_cast<const float4*>(src + 4);
  }
  __syncthreads();

#pragma unroll
  for (int r = 0; r < 16; ++r) {
    float acc = 0.f;
#pragma unroll
    for (int k4 = 0; k4 < 8; ++k4) {
      const float4 h4 = *reinterpret_cast<const float4*>(&hS[r][w * 32 + k4 * 4]);
      acc = fmaf(h4.x, Wr[k4 * 4 + 0], acc);
      acc = fmaf(h4.y, Wr[k4 * 4 + 1], acc);
      acc = fmaf(h4.z, Wr[k4 * 4 + 2], acc);
      acc = fmaf(h4.w, Wr[k4 * 4 + 3], acc);
    }
    accW[w][r][lane] = acc;
  }
  __syncthreads();

  unsigned short zt4[4];
#pragma unroll
  for (int it = 0; it < 4; ++it) {
    const int i = w * 4 + it;
    const int d = lane;
    const float zv =
        accW[0][i][d] + accW[1][i][d] + accW[2][i][d] + accW[3][i][d];
    zt4[it] = f32_to_bf16_rne(zv);
    float v1 = zv * a[d];
    float v2 = zv * a[DOUT + d];
#pragma unroll
    for (int off = 32; off; off >>= 1) {
      v1 += __shfl_xor(v1, off);
      v2 += __shfl_xor(v2, off);
    }
    if (lane == 0) {
      s1[r0 + i] = v1;
      s2[r0 + i] = v2;
    }
  }
  // store into tiled layout zT[(b*32+jb)*64 + d][jj]
  {
    const int b = zbid >> 7;
    const int bloc = zbid & 127;
    const int jb = bloc >> 2;
    const int jj0 = (bloc & 3) * 16;
    ushort4v v;
    v.x = zt4[0]; v.y = zt4[1]; v.z = zt4[2]; v.w = zt4[3];
    const size_t e =
        ((size_t)(b * (NN / 64) + jb) * DOUT + lane) * 64 + jj0 + w * 4;
    *reinterpret_cast<ushort4v*>(zT + e) = v;
  }
}

// ---- Kernel B: masked softmax + PV (bf16 MFMA) + ELU ----
// 1024 blocks (XCD-chunked swizzle: each XCD owns one batch), 4 waves.
__global__ __launch_bounds__(256, 4) void gat_attn(
    const unsigned short* __restrict__ zT, const float* __restrict__ s1g,
    const float* __restrict__ s2g, const unsigned* __restrict__ packedC,
    const int* __restrict__ mask, float* __restrict__ out) {
  // bijective XCD swizzle: dispatch id -> (b, i0) so XCD k handles batch k
  const int lid = (blockIdx.x & 7) * 128 + (blockIdx.x >> 3);
  const int b = lid >> 7;
  const int i0 = (lid & 127) * ITILE;
  const int tid = threadIdx.x;
  const int w = tid >> 6, lane = tid & 63;
  const int row16 = lane & 15, kgrp = lane >> 4;

  __shared__ unsigned short pA[NWAVE][ITILE][72];  // 9.2 KB
  __shared__ float accS[NWAVE][ITILE][DOUT];       // 16 KB
  __shared__ float Lred[NWAVE][ITILE];
  __shared__ float s1s[ITILE];
  __shared__ int mis[ITILE];

  if (tid < ITILE) {
    s1s[tid] = s1g[b * NN + i0 + tid];
    mis[tid] = mask[b * NN + i0 + tid];
  }
  __syncthreads();

  // masked-i rows: p = 1 for ALL j -> output becomes mean(z) (exact softmax
  // of a constant -9e15 row). Fill once; rows never rewritten.
#pragma unroll
  for (int i = 0; i < ITILE; ++i)
    if (!mis[i]) pA[w][i][lane] = 0x3F80;  // bf16 1.0

  float4v acc[5];
#pragma unroll
  for (int dt = 0; dt < 5; ++dt) acc[dt] = (float4v){0.f, 0.f, 0.f, 0.f};

  const short4v ones =
      (row16 == 0) ? short4v{(short)0x3F80, (short)0x3F80, (short)0x3F80,
                             (short)0x3F80}
                   : short4v{0, 0, 0, 0};

  const unsigned* pcb = packedC + (size_t)(b * 64 + (i0 >> 5)) * NN;
  const int ibit = i0 & 16;  // bit offset of row i0 inside the 32-bit word
  const unsigned short* ztb = zT + (size_t)b * (NN * DOUT);
  const int lbase = row16 * 64 + kgrp * 4;

  // ---- prologue: tile 0 ----
  unsigned aw = pcb[w * JTILE + lane];
  float s2j = s2g[b * NN + w * JTILE + lane];
  short4v bfr[16];
  {
    const unsigned short* zt0 = ztb + (size_t)w * (DOUT * 64) + lbase;
#pragma unroll
    for (int ks = 0; ks < 4; ++ks)
#pragma unroll
      for (int dt = 0; dt < 4; ++dt)
        bfr[ks * 4 + dt] = __builtin_bit_cast(
            short4v,
            *reinterpret_cast<const ushort4v*>(zt0 + dt * 1024 + ks * 16));
  }

#pragma unroll 1
  for (int t = 0; t < TTOT; ++t) {
    // issue next tile's adj-word + s2 loads FIRST (full tile of slack)
    unsigned aw_n = 0;
    float s2j_n = 0.f;
    if (t + 1 < TTOT) {
      const int j0n = ((t + 1) * NWAVE + w) * JTILE;
      aw_n = pcb[j0n + lane];
      s2j_n = s2g[b * NN + j0n + lane];
    }
    // ---- phase 1: scores -> p (bf16) into pA[w][i][lane] ----
#pragma unroll
    for (int i = 0; i < ITILE; ++i) {
      if (mis[i]) {  // block-uniform branch
        float e = s1s[i] + s2j;
        e = e > 0.f ? e : ALPHA_NS * e;
        const float pv = ((aw >> (ibit + i)) & 1u) ? __expf(e) : 0.f;
        pA[w][i][lane] = f32_to_bf16_rne(pv);
      }
    }
    // ---- phase 2: MFMA over prefetched B-fragments ----
#pragma unroll
    for (int ks = 0; ks < 4; ++ks) {
      const short4v af = __builtin_bit_cast(
          short4v,
          *reinterpret_cast<const ushort4v*>(&pA[w][row16][ks * 16 + kgrp * 4]));
      acc[4] =
          __builtin_amdgcn_mfma_f32_16x16x16bf16_1k(af, ones, acc[4], 0, 0, 0);
#pragma unroll
      for (int dt = 0; dt < 4; ++dt)
        acc[dt] = __builtin_amdgcn_mfma_f32_16x16x16bf16_1k(af, bfr[ks * 4 + dt],
                                                            acc[dt], 0, 0, 0);
    }
    // ---- issue zT fragment prefetch for t+1; rotate regs ----
    if (t + 1 < TTOT) {
      const unsigned short* ztn =
          ztb + (size_t)((t + 1) * NWAVE + w) * (DOUT * 64) + lbase;
#pragma unroll
      for (int ks = 0; ks < 4; ++ks)
#pragma unroll
        for (int dt = 0; dt < 4; ++dt)
          bfr[ks * 4 + dt] = __builtin_bit_cast(
              short4v,
              *reinterpret_cast<const ushort4v*>(ztn + dt * 1024 + ks * 16));
      aw = aw_n;
      s2j = s2j_n;
    }
  }

  // ---- stash per-wave partials ----
  if (row16 == 0) {
#pragma unroll
    for (int r = 0; r < 4; ++r) Lred[w][kgrp * 4 + r] = acc[4][r];
  }
#pragma unroll
  for (int dt = 0; dt < 4; ++dt) {
#pragma unroll
    for (int r = 0; r < 4; ++r)
      accS[w][kgrp * 4 + r][dt * 16 + row16] = acc[dt][r];
  }
  __syncthreads();

  // ---- epilogue: combine waves, divide, ELU, store ----
#pragma unroll
  for (int it = 0; it < 4; ++it) {
    const int i = (tid >> 6) + it * 4;
    const int d = tid & 63;
    const float L = Lred[0][i] + Lred[1][i] + Lred[2][i] + Lred[3][i];
    const float v = accS[0][i][d] + accS[1][i][d] + accS[2][i][d] + accS[3][i][d];
    const float hp = v / L;  // L>0: unmasked rows have a neighbor; masked rows L=N
    const float r = hp > 0.f ? hp : (__expf(hp) - 1.f);
    out[((long)b * NN + i0 + i) * DOUT + d] = r;
  }
}

extern "C" void kernel_launch(void* const* d_in, const int* in_sizes, int n_in,
                              void* d_out, int out_size, void* d_ws, size_t ws_size,
                              hipStream_t stream) {
  const float* h = (const float*)d_in[0];
  const int* adj = (const int*)d_in[1];
  const int* mask = (const int*)d_in[2];
  const float* W = (const float*)d_in[3];
  const float* a = (const float*)d_in[4];
  float* out = (float*)d_out;

  unsigned short* zT = (unsigned short*)d_ws;                   // 2 MB
  float* s1 = (float*)((char*)d_ws + (size_t)BB * NN * DOUT * 2);
  float* s2 = s1 + (size_t)BB * NN;
  unsigned* packedC = (unsigned*)(s2 + (size_t)BB * NN);        // 4 MB

  gat_prep<<<dim3(PACKBLK + BB * NN / 16), dim3(256), 0, stream>>>(
      h, W, a, adj, mask, packedC, zT, s1, s2);
  gat_attn<<<dim3(NN / ITILE * BB), dim3(256), 0, stream>>>(zT, s1, s2, packedC,
                                                            mask, out);
}

// Round 6
// 58.168 us; speedup vs baseline: 1.6125x; 1.6125x over previous
//
#include <hip/hip_runtime.h>

#define BB 8
#define NN 2048
#define DIN 128
#define DOUT 64
#define ALPHA_NS 0.2f
#define ITILE 16
#define JTILE 64
#define NWAVE 4
#define TTOT (NN / (JTILE * NWAVE))  // 8 tiles per wave
#define PACKBLK 2048                 // packer blocks in fused prep kernel

typedef __attribute__((ext_vector_type(4))) short short4v;
typedef __attribute__((ext_vector_type(4))) unsigned short ushort4v;
typedef __attribute__((ext_vector_type(4))) float float4v;

__device__ __forceinline__ unsigned short f32_to_bf16_rne(float x) {
  unsigned u = __builtin_bit_cast(unsigned, x);
  u += 0x7FFFu + ((u >> 16) & 1u);
  return (unsigned short)(u >> 16);
}

// ---- Fused prep kernel ----
// blocks [0, 2048): bit-pack adjacency (mask_j folded):
//   packedC[(b*64 + i/32)*NN + j] bit r = (adj[b][i32*32+r][j]>0 && mask[b][j]>0)
// blocks [2048, 3072): z = h@W -> zF in FRAGMENT-ORDER tiles (bf16), s1, s2.
// zF tile layout: tile jb (64 j x 64 d), element (d=dt*16+row16, jj=ks*16+kgrp*4+e)
//   at ((b*32+jb)*4096) + ((dt*4+ks)*64 + kgrp*16 + row16)*4 + e  (ushorts)
__global__ __launch_bounds__(256, 4) void gat_prep(
    const float* __restrict__ h, const float* __restrict__ W,
    const float* __restrict__ a, const int* __restrict__ adj,
    const int* __restrict__ mask, unsigned* __restrict__ packedC,
    unsigned short* __restrict__ zF, float* __restrict__ s1,
    float* __restrict__ s2) {
  __shared__ float shbuf[6144];  // union: hS (8KB) + accW (16KB)
  const int tid = threadIdx.x;
  const int w = tid >> 6, lane = tid & 63;

  if (blockIdx.x < PACKBLK) {
    // ---- packer: wave-task = (b, iw, jc): 32 i-rows x 64 j ----
    const int gw = blockIdx.x * 4 + w;  // 0..8191
#pragma unroll 1
    for (int task = gw; task < BB * 64 * 32; task += PACKBLK * 4) {
      const int jc = task & 31;
      const int iw = (task >> 5) & 63;
      const int b = task >> 11;
      const int j = jc * 64 + lane;
      const unsigned mj =
          (__builtin_nontemporal_load(mask + b * NN + j) > 0) ? 0xFFFFFFFFu : 0u;
      const int* ap = adj + ((long)(b * NN + iw * 32)) * NN + j;
      unsigned word = 0;
#pragma unroll
      for (int r = 0; r < 32; ++r)
        word |= (__builtin_nontemporal_load(ap + (long)r * NN) > 0 ? 1u : 0u) << r;
      packedC[(size_t)(b * 64 + iw) * NN + j] = word & mj;
    }
    return;
  }

  // ---- zproj ----
  const int zbid = blockIdx.x - PACKBLK;  // 0..1023
  const long r0 = (long)zbid * 16;
  float (*hS)[DIN] = reinterpret_cast<float(*)[DIN]>(shbuf);
  float (*accW)[16][DOUT] =
      reinterpret_cast<float(*)[16][DOUT]>(shbuf + 16 * DIN);

  float Wr[32];
#pragma unroll
  for (int kk = 0; kk < 32; ++kk) Wr[kk] = W[(w * 32 + kk) * DOUT + lane];

  {
    const int r = tid >> 4, c = (tid & 15) * 8;
    const float* src = h + (r0 + r) * DIN + c;
    *reinterpret_cast<float4*>(&hS[r][c]) = *reinterpret_cast<const float4*>(src);
    *reinterpret_cast<float4*>(&hS[r][c + 4]) =
        *reinterpret_cast<const float4*>(src + 4);
  }
  __syncthreads();

#pragma unroll
  for (int r = 0; r < 16; ++r) {
    float acc = 0.f;
#pragma unroll
    for (int k4 = 0; k4 < 8; ++k4) {
      const float4 h4 = *reinterpret_cast<const float4*>(&hS[r][w * 32 + k4 * 4]);
      acc = fmaf(h4.x, Wr[k4 * 4 + 0], acc);
      acc = fmaf(h4.y, Wr[k4 * 4 + 1], acc);
      acc = fmaf(h4.z, Wr[k4 * 4 + 2], acc);
      acc = fmaf(h4.w, Wr[k4 * 4 + 3], acc);
    }
    accW[w][r][lane] = acc;
  }
  __syncthreads();

  unsigned short zt4[4];
#pragma unroll
  for (int it = 0; it < 4; ++it) {
    const int i = w * 4 + it;
    const int d = lane;
    const float zv =
        accW[0][i][d] + accW[1][i][d] + accW[2][i][d] + accW[3][i][d];
    zt4[it] = f32_to_bf16_rne(zv);
    float v1 = zv * a[d];
    float v2 = zv * a[DOUT + d];
#pragma unroll
    for (int off = 32; off; off >>= 1) {
      v1 += __shfl_xor(v1, off);
      v2 += __shfl_xor(v2, off);
    }
    if (lane == 0) {
      s1[r0 + i] = v1;
      s2[r0 + i] = v2;
    }
  }
  // store into fragment-order layout: this thread's 4 i's are the e-dimension
  {
    const int b = zbid >> 7;
    const int bloc = zbid & 127;
    const int jb = bloc >> 2;       // tile index
    const int ks = bloc & 3;        // 16-j group inside tile
    const int dt = lane >> 4, row16 = lane & 15;
    ushort4v v;
    v.x = zt4[0]; v.y = zt4[1]; v.z = zt4[2]; v.w = zt4[3];
    const size_t e = ((size_t)(b * 32 + jb)) * 4096 +
                     (size_t)(((dt * 4 + ks) * 64 + w * 16 + row16) * 4);
    *reinterpret_cast<ushort4v*>(zF + e) = v;
  }
}

// ---- Kernel B: masked softmax + PV (bf16 MFMA) + ELU ----
// 1024 blocks (XCD-chunked swizzle: each XCD owns one batch), 4 waves.
__global__ __launch_bounds__(256, 4) void gat_attn(
    const unsigned short* __restrict__ zF, const float* __restrict__ s1g,
    const float* __restrict__ s2g, const unsigned* __restrict__ packedC,
    const int* __restrict__ mask, float* __restrict__ out) {
  const int lid = (blockIdx.x & 7) * 128 + (blockIdx.x >> 3);
  const int b = lid >> 7;
  const int i0 = (lid & 127) * ITILE;
  const int tid = threadIdx.x;
  const int w = tid >> 6, lane = tid & 63;
  const int row16 = lane & 15, kgrp = lane >> 4;

  __shared__ unsigned short pA[NWAVE][ITILE][72];  // 9.2 KB
  __shared__ float accS[NWAVE][ITILE][DOUT];       // 16 KB
  __shared__ float Lred[NWAVE][ITILE];
  __shared__ float s1s[ITILE];
  __shared__ int mis[ITILE];

  if (tid < ITILE) {
    s1s[tid] = s1g[b * NN + i0 + tid];
    mis[tid] = mask[b * NN + i0 + tid];
  }
  __syncthreads();

  // masked-i rows: p = 1 for ALL j -> output = mean(z) exactly
#pragma unroll
  for (int i = 0; i < ITILE; ++i)
    if (!mis[i]) pA[w][i][lane] = 0x3F80;  // bf16 1.0

  float4v acc[5];
#pragma unroll
  for (int dt = 0; dt < 5; ++dt) acc[dt] = (float4v){0.f, 0.f, 0.f, 0.f};

  const short4v ones =
      (row16 == 0) ? short4v{(short)0x3F80, (short)0x3F80, (short)0x3F80,
                             (short)0x3F80}
                   : short4v{0, 0, 0, 0};

  const unsigned* pcb = packedC + (size_t)(b * 64 + (i0 >> 5)) * NN;
  const int ibit = i0 & 16;
  const unsigned short* ztb = zF + (size_t)(b * 32) * 4096;

  // ---- prologue: tile 0 (jb = w) ----
  unsigned aw = pcb[w * JTILE + lane];
  float s2j = s2g[b * NN + w * JTILE + lane];
  short4v bfr[16];
  {
    const unsigned short* t0 = ztb + (size_t)w * 4096 + lane * 4;
#pragma unroll
    for (int ks = 0; ks < 4; ++ks)
#pragma unroll
      for (int dt = 0; dt < 4; ++dt)
        bfr[ks * 4 + dt] = __builtin_bit_cast(
            short4v,
            *reinterpret_cast<const ushort4v*>(t0 + (dt * 4 + ks) * 256));
  }

#pragma unroll 1
  for (int t = 0; t < TTOT; ++t) {
    // issue next tile's adj-word + s2 loads first (a full tile of slack)
    unsigned aw_n = 0;
    float s2j_n = 0.f;
    if (t + 1 < TTOT) {
      const int j0n = ((t + 1) * NWAVE + w) * JTILE;
      aw_n = pcb[j0n + lane];
      s2j_n = s2g[b * NN + j0n + lane];
    }
    // ---- phase 1: scores -> p (bf16) into pA[w][i][lane] ----
#pragma unroll
    for (int i = 0; i < ITILE; ++i) {
      if (mis[i]) {  // block-uniform branch
        float e = s1s[i] + s2j;
        e = e > 0.f ? e : ALPHA_NS * e;
        const float pv = ((aw >> (ibit + i)) & 1u) ? __expf(e) : 0.f;
        pA[w][i][lane] = f32_to_bf16_rne(pv);
      }
    }
    // ---- phase 2: MFMA over prefetched B-fragments ----
#pragma unroll
    for (int ks = 0; ks < 4; ++ks) {
      const short4v af = __builtin_bit_cast(
          short4v,
          *reinterpret_cast<const ushort4v*>(&pA[w][row16][ks * 16 + kgrp * 4]));
      acc[4] =
          __builtin_amdgcn_mfma_f32_16x16x16bf16_1k(af, ones, acc[4], 0, 0, 0);
#pragma unroll
      for (int dt = 0; dt < 4; ++dt)
        acc[dt] = __builtin_amdgcn_mfma_f32_16x16x16bf16_1k(af, bfr[ks * 4 + dt],
                                                            acc[dt], 0, 0, 0);
    }
    // ---- issue zF fragment prefetch for t+1 (coalesced 512B per inst) ----
    if (t + 1 < TTOT) {
      const unsigned short* tn =
          ztb + (size_t)((t + 1) * 4 + w) * 4096 + lane * 4;
#pragma unroll
      for (int ks = 0; ks < 4; ++ks)
#pragma unroll
        for (int dt = 0; dt < 4; ++dt)
          bfr[ks * 4 + dt] = __builtin_bit_cast(
              short4v,
              *reinterpret_cast<const ushort4v*>(tn + (dt * 4 + ks) * 256));
      aw = aw_n;
      s2j = s2j_n;
    }
  }

  // ---- stash per-wave partials ----
  if (row16 == 0) {
#pragma unroll
    for (int r = 0; r < 4; ++r) Lred[w][kgrp * 4 + r] = acc[4][r];
  }
#pragma unroll
  for (int dt = 0; dt < 4; ++dt) {
#pragma unroll
    for (int r = 0; r < 4; ++r)
      accS[w][kgrp * 4 + r][dt * 16 + row16] = acc[dt][r];
  }
  __syncthreads();

  // ---- epilogue: combine waves, divide, ELU, store ----
#pragma unroll
  for (int it = 0; it < 4; ++it) {
    const int i = (tid >> 6) + it * 4;
    const int d = tid & 63;
    const float L = Lred[0][i] + Lred[1][i] + Lred[2][i] + Lred[3][i];
    const float v = accS[0][i][d] + accS[1][i][d] + accS[2][i][d] + accS[3][i][d];
    const float hp = v / L;
    const float r = hp > 0.f ? hp : (__expf(hp) - 1.f);
    out[((long)b * NN + i0 + i) * DOUT + d] = r;
  }
}

extern "C" void kernel_launch(void* const* d_in, const int* in_sizes, int n_in,
                              void* d_out, int out_size, void* d_ws, size_t ws_size,
                              hipStream_t stream) {
  const float* h = (const float*)d_in[0];
  const int* adj = (const int*)d_in[1];
  const int* mask = (const int*)d_in[2];
  const float* W = (const float*)d_in[3];
  const float* a = (const float*)d_in[4];
  float* out = (float*)d_out;

  unsigned short* zF = (unsigned short*)d_ws;                   // 2 MB
  float* s1 = (float*)((char*)d_ws + (size_t)BB * NN * DOUT * 2);
  float* s2 = s1 + (size_t)BB * NN;
  unsigned* packedC = (unsigned*)(s2 + (size_t)BB * NN);        // 4 MB

  gat_prep<<<dim3(PACKBLK + BB * NN / 16), dim3(256), 0, stream>>>(
      h, W, a, adj, mask, packedC, zF, s1, s2);
  gat_attn<<<dim3(NN / ITILE * BB), dim3(256), 0, stream>>>(zF, s1, s2, packedC,
                                                            mask, out);
}